// Round 4
// baseline (418.244 us; speedup 1.0000x reference)
//
#include <hip/hip_runtime.h>

// Lyapunov spectrum via chunked QR scan with warm-up re-convergence.
// inp: (T=4096, 9, B=2048) fp32.  out: (3, B) fp32.
// R4: TLP over per-wave pipelining. BPT=1, NCHUNK=128 -> 4096 waves
//     (4/SIMD on all 1024 SIMDs); WARM=24 (gap 0.307/step, e^-7.4 mean seam
//     contraction); traffic 1.75x input = 529 MB -> HBM floor ~84us.
//     PF=4 register ring retained (helps, TLP makes it non-critical).

constexpr int T_STEPS = 4096;
constexpr int BATCH   = 2048;
constexpr int NCHUNK  = 128;
constexpr int KSEG    = T_STEPS / NCHUNK;  // 32
constexpr int WARM    = 24;                // divisible by PF
constexpr int PF      = 4;                 // prefetch ring depth

__device__ __forceinline__ void lya_step(const float J[9], float Q[9], float d[3]) {
    // M = J * Q  (per-batch 3x3 matmul), M[i*3+j]
    float M[9];
#pragma unroll
    for (int i = 0; i < 3; ++i) {
#pragma unroll
        for (int j = 0; j < 3; ++j) {
            M[i * 3 + j] = J[i * 3 + 0] * Q[0 * 3 + j]
                         + J[i * 3 + 1] * Q[1 * 3 + j]
                         + J[i * 3 + 2] * Q[2 * 3 + j];
        }
    }
    // Classical Gram-Schmidt (projections vs original cols), 1/d = rsq^2
    float b0x = M[0], b0y = M[3], b0z = M[6];
    float d00 = b0x * b0x + b0y * b0y + b0z * b0z;
    float r0 = __builtin_amdgcn_rsqf(d00);
    float inv00 = r0 * r0;

    float x1x = M[1], x1y = M[4], x1z = M[7];
    float c01 = (b0x * x1x + b0y * x1y + b0z * x1z) * inv00;
    float b1x = x1x - c01 * b0x;
    float b1y = x1y - c01 * b0y;
    float b1z = x1z - c01 * b0z;
    float d11 = b1x * b1x + b1y * b1y + b1z * b1z;
    float r1 = __builtin_amdgcn_rsqf(d11);
    float inv11 = r1 * r1;

    float x2x = M[2], x2y = M[5], x2z = M[8];
    float c02 = (b0x * x2x + b0y * x2y + b0z * x2z) * inv00;
    float c12 = (b1x * x2x + b1y * x2y + b1z * x2z) * inv11;
    float b2x = x2x - c02 * b0x - c12 * b1x;
    float b2y = x2y - c02 * b0y - c12 * b1y;
    float b2z = x2z - c02 * b0z - c12 * b1z;
    float d22 = b2x * b2x + b2y * b2y + b2z * b2z;
    float r2 = __builtin_amdgcn_rsqf(d22);

    Q[0] = b0x * r0; Q[3] = b0y * r0; Q[6] = b0z * r0;
    Q[1] = b1x * r1; Q[4] = b1y * r1; Q[7] = b1z * r1;
    Q[2] = b2x * r2; Q[5] = b2y * r2; Q[8] = b2z * r2;
    d[0] = d00; d[1] = d11; d[2] = d22;
}

__global__ __launch_bounds__(256) void lya_kernel(const float* __restrict__ inp,
                                                  float* __restrict__ out) {
    const int tid   = blockIdx.x * 256 + threadIdx.x;
    const int b     = tid & (BATCH - 1);
    const int chunk = tid >> 11;           // 2048 threads/chunk -> wave-uniform
    const int kacc  = chunk * KSEG;
    const int s0    = (kacc >= WARM) ? (kacc - WARM) : 0;
    const int nwarm = kacc - s0;           // 0 (chunk 0) or WARM

    float Q[9] = {1.f, 0.f, 0.f,
                  0.f, 1.f, 0.f,
                  0.f, 0.f, 1.f};
    float acc0 = 0.f, acc1 = 0.f, acc2 = 0.f;

    // Preload PF-deep ring: steps s0 .. s0+PF-1 (s0+PF-1 <= 4040+3 < 4096).
    float Jb[PF][9];
#pragma unroll
    for (int r = 0; r < PF; ++r) {
        const float* p = inp + (size_t)(s0 + r) * 9 * BATCH + b;
#pragma unroll
        for (int m = 0; m < 9; ++m) Jb[r][m] = p[(size_t)m * BATCH];
    }

    float d[3];

    // Warm-up: re-converge Q, discard log-norms. Prefetch t = s0+i+r+PF,
    // always <= kacc+PF-1 < 4096.
    for (int i = 0; i < nwarm; i += PF) {
#pragma unroll
        for (int r = 0; r < PF; ++r) {
            lya_step(Jb[r], Q, d);
            const float* p = inp + (size_t)(s0 + i + r + PF) * 9 * BATCH + b;
#pragma unroll
            for (int m = 0; m < 9; ++m) Jb[r][m] = p[(size_t)m * BATCH];
        }
    }

    // Accumulation: product-of-PF then one log2 per column.
    for (int i = nwarm; i < nwarm + KSEG; i += PF) {
        float p0 = 1.f, p1 = 1.f, p2 = 1.f;
#pragma unroll
        for (int r = 0; r < PF; ++r) {
            lya_step(Jb[r], Q, d);
            p0 *= d[0]; p1 *= d[1]; p2 *= d[2];
            int tp = s0 + i + r + PF;
            if (tp > T_STEPS - 1) tp = T_STEPS - 1;   // tail: clamped redundant read
            const float* p = inp + (size_t)tp * 9 * BATCH + b;
#pragma unroll
            for (int m = 0; m < 9; ++m) Jb[r][m] = p[(size_t)m * BATCH];
        }
        acc0 += __log2f(p0);
        acc1 += __log2f(p1);
        acc2 += __log2f(p2);
    }

    // log||b|| = 0.5*ln2*log2(d);  Lya = sum / (T*dt)
    const float scale = 0.5f * 0.69314718056f / (T_STEPS * 0.01f);
    atomicAdd(&out[0 * BATCH + b], acc0 * scale);
    atomicAdd(&out[1 * BATCH + b], acc1 * scale);
    atomicAdd(&out[2 * BATCH + b], acc2 * scale);
}

extern "C" void kernel_launch(void* const* d_in, const int* in_sizes, int n_in,
                              void* d_out, int out_size, void* d_ws, size_t ws_size,
                              hipStream_t stream) {
    const float* inp = (const float*)d_in[0];
    float* out = (float*)d_out;

    hipMemsetAsync(out, 0, (size_t)out_size * sizeof(float), stream);

    // NCHUNK * BATCH threads = 262144 -> 1024 blocks of 256 -> 4096 waves.
    dim3 grid(NCHUNK * BATCH / 256);
    dim3 block(256);
    lya_kernel<<<grid, block, 0, stream>>>(inp, out);
}